// Round 9
// baseline (1699.242 us; speedup 1.0000x reference)
//
#include <hip/hip_runtime.h>

#define NN 100000
#define EE 1600000
#define HH 128
#define MM 256
#define LL 6
#define GG 512
#define SCAN_NB ((NN + 1023) / 1024)

typedef __attribute__((ext_vector_type(8))) short short8;
typedef __attribute__((ext_vector_type(4))) float floatx4;

__device__ __forceinline__ float swishf(float v) {
    return v / (1.0f + __expf(-v));
}

__device__ __forceinline__ unsigned short f2bf(float f) {
    unsigned u = __builtin_bit_cast(unsigned, f);
    unsigned r = u + 0x7FFFu + ((u >> 16) & 1u);
    return (unsigned short)(r >> 16);
}

__device__ __forceinline__ float bf2f(unsigned short u) {
    return __builtin_bit_cast(float, (unsigned)u << 16);
}

__device__ __forceinline__ float2 bf2f2(unsigned u) {
    float2 r;
    r.x = __builtin_bit_cast(float, u << 16);
    r.y = __builtin_bit_cast(float, u & 0xFFFF0000u);
    return r;
}

__device__ __forceinline__ void unpack8(uint4 v, float* a) {
    float2 p0 = bf2f2(v.x), p1 = bf2f2(v.y), p2 = bf2f2(v.z), p3 = bf2f2(v.w);
    a[0] = p0.x; a[1] = p0.y; a[2] = p1.x; a[3] = p1.y;
    a[4] = p2.x; a[5] = p2.y; a[6] = p3.x; a[7] = p3.y;
}

__device__ __forceinline__ uint4 pack8(const float* o) {
    uint4 pk;
    pk.x = (unsigned)f2bf(o[0]) | ((unsigned)f2bf(o[1]) << 16);
    pk.y = (unsigned)f2bf(o[2]) | ((unsigned)f2bf(o[3]) << 16);
    pk.z = (unsigned)f2bf(o[4]) | ((unsigned)f2bf(o[5]) << 16);
    pk.w = (unsigned)f2bf(o[6]) | ((unsigned)f2bf(o[7]) << 16);
    return pk;
}

__device__ __forceinline__ uint2 pack4(const float* o) {
    uint2 pk;
    pk.x = (unsigned)f2bf(o[0]) | ((unsigned)f2bf(o[1]) << 16);
    pk.y = (unsigned)f2bf(o[2]) | ((unsigned)f2bf(o[3]) << 16);
    return pk;
}

// h[n,c] (row-major bf16) = z_embed[z[n],c] + x[:,1:]@ew^T + eb
__global__ void k_embed(const float* __restrict__ x, const float* __restrict__ z_embed,
                        const float* __restrict__ ew, const float* __restrict__ eb,
                        unsigned short* __restrict__ hb) {
    int idx = blockIdx.x * blockDim.x + threadIdx.x;
    if (idx >= NN * 32) return;
    int n = idx >> 5;
    int c0 = (idx & 31) << 2;
    const float* xr = x + (size_t)n * 4;
    int z = (int)xr[0];
    float x1 = xr[1], x2 = xr[2], x3 = xr[3];
    const float* ze = z_embed + (size_t)z * HH + c0;
    float o[4];
#pragma unroll
    for (int j = 0; j < 4; ++j) {
        int c = c0 + j;
        o[j] = ze[j] + x1 * ew[c * 3 + 0] + x2 * ew[c * 3 + 1] + x3 * ew[c * 3 + 2] + eb[c];
    }
    *(uint2*)(hb + (size_t)n * HH + c0) = pack4(o);
}

__global__ void k_f2bf3(const float* __restrict__ s1, unsigned short* __restrict__ d1, int n1,
                        const float* __restrict__ s2, unsigned short* __restrict__ d2, int n2,
                        const float* __restrict__ s3, unsigned short* __restrict__ d3, int n3) {
    int i = blockIdx.x * blockDim.x + threadIdx.x;
    if (i < n1) {
        d1[i] = f2bf(s1[i]);
    } else if (i < n1 + n2) {
        d2[i - n1] = f2bf(s2[i - n1]);
    } else if (i < n1 + n2 + n3) {
        d3[i - n1 - n2] = f2bf(s3[i - n1 - n2]);
    }
}

__global__ __launch_bounds__(256) void k_degree_p(const int* __restrict__ dst,
                                                  int* __restrict__ deg) {
    int part = blockIdx.x & 7;
    int blk = blockIdx.x >> 3;
    int nb = gridDim.x >> 3;
    int lo = (int)((long long)part * NN / 8);
    int hi = (int)((long long)(part + 1) * NN / 8);
    for (int e = blk * 256 + threadIdx.x; e < EE; e += nb * 256) {
        int d = dst[e];
        if (d >= lo && d < hi) atomicAdd(&deg[d], 1);
    }
}

__global__ void k_dinv(const int* __restrict__ deg, float* __restrict__ dinv) {
    int n = blockIdx.x * blockDim.x + threadIdx.x;
    if (n < NN) dinv[n] = rsqrtf((float)(deg[n] + 1));
}

__global__ void k_scan1(const int* __restrict__ deg, int* __restrict__ bsum) {
    __shared__ int sd[256];
    int t = threadIdx.x;
    int base = blockIdx.x * 1024 + t * 4;
    int s = 0;
#pragma unroll
    for (int j = 0; j < 4; ++j) {
        int i = base + j;
        if (i < NN) s += deg[i];
    }
    sd[t] = s;
    __syncthreads();
    for (int off = 128; off > 0; off >>= 1) {
        if (t < off) sd[t] += sd[t + off];
        __syncthreads();
    }
    if (t == 0) bsum[blockIdx.x] = sd[0];
}

__global__ void k_scan2(const int* __restrict__ bsum, int* __restrict__ boff) {
    __shared__ int sd[128];
    int t = threadIdx.x;
    int v = (t < SCAN_NB) ? bsum[t] : 0;
    sd[t] = v;
    __syncthreads();
    for (int off = 1; off < 128; off <<= 1) {
        int u = (t >= off) ? sd[t - off] : 0;
        __syncthreads();
        sd[t] += u;
        __syncthreads();
    }
    boff[t] = sd[t] - v;  // exclusive
}

__global__ void k_scan3(const int* __restrict__ deg, const int* __restrict__ boff,
                        int* __restrict__ rowptr) {
    __shared__ int sd[256];
    int t = threadIdx.x;
    int base = blockIdx.x * 1024 + t * 4;
    int v[4];
    int s = 0;
#pragma unroll
    for (int j = 0; j < 4; ++j) {
        int i = base + j;
        v[j] = (i < NN) ? deg[i] : 0;
        s += v[j];
    }
    sd[t] = s;
    __syncthreads();
    for (int off = 1; off < 256; off <<= 1) {
        int u = (t >= off) ? sd[t - off] : 0;
        __syncthreads();
        sd[t] += u;
        __syncthreads();
    }
    int run = boff[blockIdx.x] + sd[t] - s;
#pragma unroll
    for (int j = 0; j < 4; ++j) {
        int i = base + j;
        if (i < NN) rowptr[i] = run;
        if (i == NN - 1) rowptr[NN] = run + v[j];
        run += v[j];
    }
}

__global__ __launch_bounds__(256) void k_fill_p(const int* __restrict__ ei,
                                                const int* __restrict__ rowptr,
                                                int* __restrict__ cursor,
                                                int* __restrict__ col) {
    int part = blockIdx.x & 7;
    int blk = blockIdx.x >> 3;
    int nb = gridDim.x >> 3;
    int lo = (int)((long long)part * NN / 8);
    int hi = (int)((long long)(part + 1) * NN / 8);
    for (int e = blk * 256 + threadIdx.x; e < EE; e += nb * 256) {
        int d = ei[EE + e];
        if (d >= lo && d < hi) {
            int p = atomicAdd(&cursor[d], 1);
            col[rowptr[d] + p] = ei[e];
        }
    }
}

__global__ void k_gptr(const int* __restrict__ batch, int* __restrict__ gptr) {
    int n = blockIdx.x * blockDim.x + threadIdx.x;
    if (n >= NN) return;
    int b = batch[n];
    int pb = (n == 0) ? -1 : batch[n - 1];
    for (int g = pb + 1; g <= b; ++g) gptr[g] = n;
    if (n == NN - 1) {
        for (int g = b + 1; g <= GG; ++g) gptr[g] = NN;
    }
}

// Conv GEMM (layer 0 only): y = bf16((h @ Wc^T) * dinv[row]).
__global__ __launch_bounds__(256) void k_conv(const unsigned short* __restrict__ A,
                                              const unsigned short* __restrict__ B,
                                              const float* __restrict__ dinv,
                                              unsigned short* __restrict__ Cb) {
    __shared__ unsigned short Bs[128][HH + 8];
    const int tid = threadIdx.x;
    const int wave = tid >> 6;
    const int lane = tid & 63;
    const int quad = lane >> 4;
    const int l16 = lane & 15;
    const int wr = (wave & 1) << 6;
    const int wc = (wave >> 1) << 6;
    const int rowBase = blockIdx.x * 128;

    for (int i = tid; i < 128 * (HH / 8); i += 256) {
        int r = i / (HH / 8);
        int kk = (i % (HH / 8)) * 8;
        int rho = (r & 64) | ((r & 3) << 4) | ((r >> 2) & 15);
        *(uint4*)(&Bs[rho][kk]) = *(const uint4*)(B + (size_t)r * HH + kk);
    }

    floatx4 acc[4][4];
    const floatx4 zed = {0.f, 0.f, 0.f, 0.f};
#pragma unroll
    for (int i = 0; i < 4; ++i)
#pragma unroll
        for (int j = 0; j < 4; ++j) acc[i][j] = zed;

    int ar[4];
#pragma unroll
    for (int i = 0; i < 4; ++i) {
        int r = rowBase + wr + (i << 4) + l16;
        ar[i] = r < NN ? r : NN - 1;
    }

    __syncthreads();

#pragma unroll
    for (int ks = 0; ks < HH / 32; ++ks) {
        int k = (ks << 5) + (quad << 3);
        short8 a[4], b[4];
#pragma unroll
        for (int i = 0; i < 4; ++i) a[i] = *(const short8*)(A + (size_t)ar[i] * HH + k);
#pragma unroll
        for (int j = 0; j < 4; ++j) b[j] = *(const short8*)(&Bs[wc + (j << 4) + l16][k]);
#pragma unroll
        for (int i = 0; i < 4; ++i)
#pragma unroll
            for (int j = 0; j < 4; ++j)
                acc[i][j] =
                    __builtin_amdgcn_mfma_f32_16x16x32_bf16(a[i], b[j], acc[i][j], 0, 0, 0);
    }

    const int c0 = wc + (l16 << 2);
#pragma unroll
    for (int i = 0; i < 4; ++i) {
        int rb = rowBase + wr + (i << 4) + (quad << 2);
#pragma unroll
        for (int reg = 0; reg < 4; ++reg) {
            int r = rb + reg;
            if (r < NN) {
                float dv = dinv[r];
                float o[4];
#pragma unroll
                for (int j = 0; j < 4; ++j) o[j] = acc[i][j][reg] * dv;
                *(uint2*)(Cb + (size_t)r * HH + c0) = pack4(o);
            }
        }
    }
}

// Wide-load gather (row-major): wave = 1 node; 16 lanes x 16 B cover the 256 B row.
__global__ __launch_bounds__(256) void k_agg(const unsigned short* __restrict__ y,
                                             const int* __restrict__ rowptr,
                                             const int* __restrict__ col,
                                             const float* __restrict__ dinv,
                                             const float* __restrict__ cb,
                                             unsigned short* __restrict__ agg) {
    int w = threadIdx.x >> 6;
    int lane = threadIdx.x & 63;
    int d = blockIdx.x * 4 + w;
    if (d >= NN) return;
    int grp = lane >> 4;
    int l16 = lane & 15;
    const uint4* yv = (const uint4*)y;
    float acc[8];
#pragma unroll
    for (int j = 0; j < 8; ++j) acc[j] = 0.f;
    if (grp == 0) {
        uint4 v = yv[(size_t)d * 16 + l16];
        unpack8(v, acc);
    }
    int beg = rowptr[d];
    int end = rowptr[d + 1];
    for (int e = beg + grp; e < end; e += 4) {
        int s = col[e];
        uint4 v = yv[(size_t)s * 16 + l16];
        float b0[8];
        unpack8(v, b0);
#pragma unroll
        for (int k = 0; k < 8; ++k) acc[k] += b0[k];
    }
#pragma unroll
    for (int j = 0; j < 8; ++j) {
        acc[j] += __shfl_xor(acc[j], 16, 64);
        acc[j] += __shfl_xor(acc[j], 32, 64);
    }
    if (grp == 0) {
        float dv = dinv[d];
        float4 c0 = *(const float4*)(cb + l16 * 8);
        float4 c1 = *(const float4*)(cb + l16 * 8 + 4);
        float o[8];
        o[0] = acc[0] * dv + c0.x; o[1] = acc[1] * dv + c0.y;
        o[2] = acc[2] * dv + c0.z; o[3] = acc[3] * dv + c0.w;
        o[4] = acc[4] * dv + c1.x; o[5] = acc[5] * dv + c1.y;
        o[6] = acc[6] * dv + c1.z; o[7] = acc[7] * dv + c1.w;
        *(uint4*)(agg + (size_t)d * HH + l16 * 8) = pack8(o);
    }
}

// per-graph stats -> affine coeffs: c1 = gamma*rstd, c0 = beta - c1*ms*mean
__global__ __launch_bounds__(512) void k_stats(const unsigned short* __restrict__ agg,
                                               const int* __restrict__ gptr,
                                               const float* __restrict__ ms,
                                               const float* __restrict__ gamma,
                                               const float* __restrict__ beta,
                                               float* __restrict__ c1,
                                               float* __restrict__ c0) {
    __shared__ float s1[512];
    __shared__ float s2[512];
    int g = blockIdx.x;
    int t = threadIdx.x;
    int c = t & 127;
    int part = t >> 7;
    int beg = gptr[g];
    int end = gptr[g + 1];
    float S1 = 0.f, S2 = 0.f;
    for (int n = beg + part; n < end; n += 4) {
        float v = bf2f(agg[(size_t)n * HH + c]);
        S1 += v;
        S2 += v * v;
    }
    s1[t] = S1;
    s2[t] = S2;
    __syncthreads();
    if (part == 0) {
        S1 = (s1[c] + s1[c + 128]) + (s1[c + 256] + s1[c + 384]);
        S2 = (s2[c] + s2[c + 128]) + (s2[c + 256] + s2[c + 384]);
        int cnt = end - beg;
        float inv = 1.0f / (float)(cnt > 0 ? cnt : 1);
        float m = S1 * inv;
        float msc = ms[c];
        float var = S2 * inv - msc * (2.0f - msc) * m * m;
        float rstd = rsqrtf(var + 1e-5f);
        float c1v = gamma[c] * rstd;
        c1[g * HH + c] = c1v;
        c0[g * HH + c] = beta[c] - c1v * msc * m;
    }
}

// Mega layer kernel, 512 threads / 64 rows: 8 waves = 4 row-groups x 2 col-halves.
// Phase A: ha = swish(c1*agg+c0) inline; t = swish(ha@W1^T+b1) -> LDS (64x264).
// Phase B: h' = swish(t@W2^T+b2)+res -> hb (+h_out if writeF), h' -> LDS (pitch 136).
// Phase C (doConv): y_next = bf16((h'@Wc^T)*dinv).
__global__ __launch_bounds__(512) void k_mega(const unsigned short* __restrict__ agg,
                                              const int* __restrict__ batch,
                                              const float* __restrict__ c1,
                                              const float* __restrict__ c0,
                                              const unsigned short* __restrict__ W1,
                                              const float* __restrict__ b1,
                                              const unsigned short* __restrict__ W2,
                                              const float* __restrict__ b2,
                                              const unsigned short* __restrict__ Wc,
                                              const float* __restrict__ dinv,
                                              unsigned short* __restrict__ hb,
                                              float* __restrict__ h_out,
                                              unsigned short* __restrict__ y_out, int writeF,
                                              int doConv) {
    __shared__ unsigned short smem[64 * (MM + 8)];  // t pitch 264; reused as h' pitch 136
    const int tid = threadIdx.x;
    const int wave = tid >> 6;
    const int lane = tid & 63;
    const int quad = lane >> 4;
    const int l16 = lane & 15;
    const int rg = (wave & 3) << 4;    // row group 0/16/32/48
    const int ch = (wave >> 2) << 7;   // t-col half 0/128
    const int co2 = (wave >> 2) << 6;  // out-col half 0/64
    const int rowBase = blockIdx.x * 64;
    const floatx4 zed = {0.f, 0.f, 0.f, 0.f};

    // ---- phase A: normswished A-fragments; t = swish(. @ W1^T + b1) ----
    int r0 = rowBase + rg + l16;
    int ar = r0 < NN ? r0 : NN - 1;
    int gi = batch[ar];

    short8 a_all[4];
#pragma unroll
    for (int ks = 0; ks < 4; ++ks) {
        int k = (ks << 5) + (quad << 3);
        uint4 raw = *(const uint4*)(agg + (size_t)ar * HH + k);
        float v[8];
        unpack8(raw, v);
        const float* c1p = c1 + gi * HH + k;
        const float* c0p = c0 + gi * HH + k;
        float4 c1a = *(const float4*)c1p;
        float4 c1b = *(const float4*)(c1p + 4);
        float4 c0a = *(const float4*)c0p;
        float4 c0b = *(const float4*)(c0p + 4);
        float cc1[8] = {c1a.x, c1a.y, c1a.z, c1a.w, c1b.x, c1b.y, c1b.z, c1b.w};
        float cc0[8] = {c0a.x, c0a.y, c0a.z, c0a.w, c0b.x, c0b.y, c0b.z, c0b.w};
        short8 av;
#pragma unroll
        for (int j = 0; j < 8; ++j) av[j] = (short)f2bf(swishf(cc1[j] * v[j] + cc0[j]));
        a_all[ks] = av;
    }

    floatx4 acc1[8];
#pragma unroll
    for (int j = 0; j < 8; ++j) acc1[j] = zed;
    const int c0a = ch + (l16 << 3);  // 8 adjacent t-cols per lane
#pragma unroll
    for (int ks = 0; ks < 4; ++ks) {
        int k = (ks << 5) + (quad << 3);
        short8 b[8];
#pragma unroll
        for (int j = 0; j < 8; ++j) b[j] = *(const short8*)(W1 + (size_t)(c0a + j) * HH + k);
#pragma unroll
        for (int j = 0; j < 8; ++j)
            acc1[j] = __builtin_amdgcn_mfma_f32_16x16x32_bf16(a_all[ks], b[j], acc1[j], 0, 0, 0);
    }
    {
        float4 u = *(const float4*)(b1 + c0a);
        float4 w = *(const float4*)(b1 + c0a + 4);
        float bv[8] = {u.x, u.y, u.z, u.w, w.x, w.y, w.z, w.w};
#pragma unroll
        for (int reg = 0; reg < 4; ++reg) {
            int lr = rg + (quad << 2) + reg;
            float o[8];
#pragma unroll
            for (int j = 0; j < 8; ++j) o[j] = swishf(acc1[j][reg] + bv[j]);
            *(uint4*)(&smem[lr * (MM + 8) + c0a]) = pack8(o);
        }
    }
    __syncthreads();

    // ---- phase B: h' = swish(t @ W2^T + b2) + res ----
    floatx4 acc2[4];
#pragma unroll
    for (int j = 0; j < 4; ++j) acc2[j] = zed;
    const int co = co2 + (l16 << 2);
#pragma unroll
    for (int ks = 0; ks < MM / 32; ++ks) {
        int k = (ks << 5) + (quad << 3);
        short8 a = *(const short8*)(&smem[(rg + l16) * (MM + 8) + k]);
        short8 b[4];
#pragma unroll
        for (int j = 0; j < 4; ++j) b[j] = *(const short8*)(W2 + (size_t)(co + j) * MM + k);
#pragma unroll
        for (int j = 0; j < 4; ++j)
            acc2[j] = __builtin_amdgcn_mfma_f32_16x16x32_bf16(a, b[j], acc2[j], 0, 0, 0);
    }
    __syncthreads();  // t reads done; smem reusable as h'

    {
        float4 b4 = *(const float4*)(b2 + co);
        float bv[4] = {b4.x, b4.y, b4.z, b4.w};
#pragma unroll
        for (int reg = 0; reg < 4; ++reg) {
            int lr = rg + (quad << 2) + reg;
            int r = rowBase + lr;
            if (r < NN) {
                uint2 rv = *(const uint2*)(hb + (size_t)r * HH + co);
                float2 r01 = bf2f2(rv.x), r23 = bf2f2(rv.y);
                float o[4];
                o[0] = swishf(acc2[0][reg] + bv[0]) + r01.x;
                o[1] = swishf(acc2[1][reg] + bv[1]) + r01.y;
                o[2] = swishf(acc2[2][reg] + bv[2]) + r23.x;
                o[3] = swishf(acc2[3][reg] + bv[3]) + r23.y;
                uint2 pk = pack4(o);
                *(uint2*)(hb + (size_t)r * HH + co) = pk;
                if (writeF)
                    *(float4*)(h_out + (size_t)r * HH + co) = make_float4(o[0], o[1], o[2], o[3]);
                *(uint2*)(&smem[lr * 136 + co]) = pk;
            } else {
                // keep LDS defined for phase C reads
                *(uint2*)(&smem[lr * 136 + co]) = make_uint2(0u, 0u);
            }
        }
    }

    // ---- phase C: y_next = bf16((h' @ Wc^T) * dinv) ----
    if (doConv) {
        __syncthreads();
        floatx4 acc3[4];
#pragma unroll
        for (int j = 0; j < 4; ++j) acc3[j] = zed;
#pragma unroll
        for (int ks = 0; ks < 4; ++ks) {
            int k = (ks << 5) + (quad << 3);
            short8 a = *(const short8*)(&smem[(rg + l16) * 136 + k]);
            short8 b[4];
#pragma unroll
            for (int j = 0; j < 4; ++j) b[j] = *(const short8*)(Wc + (size_t)(co + j) * HH + k);
#pragma unroll
            for (int j = 0; j < 4; ++j)
                acc3[j] = __builtin_amdgcn_mfma_f32_16x16x32_bf16(a, b[j], acc3[j], 0, 0, 0);
        }
#pragma unroll
        for (int reg = 0; reg < 4; ++reg) {
            int r = rowBase + rg + (quad << 2) + reg;
            if (r < NN) {
                float dv = dinv[r];
                float o[4];
#pragma unroll
                for (int j = 0; j < 4; ++j) o[j] = acc3[j][reg] * dv;
                *(uint2*)(y_out + (size_t)r * HH + co) = pack4(o);
            }
        }
    }
}

extern "C" void kernel_launch(void* const* d_in, const int* in_sizes, int n_in,
                              void* d_out, int out_size, void* d_ws, size_t ws_size,
                              hipStream_t stream) {
    const float* x = (const float*)d_in[0];
    const int* ei = (const int*)d_in[1];
    const int* batch = (const int*)d_in[2];
    const float* z_embed = (const float*)d_in[3];
    const float* extra_w = (const float*)d_in[4];
    const float* extra_b = (const float*)d_in[5];
    const float* conv_w = (const float*)d_in[6];
    const float* conv_b = (const float*)d_in[7];
    const float* gamma = (const float*)d_in[8];
    const float* beta = (const float*)d_in[9];
    const float* mean_scale = (const float*)d_in[10];
    const float* mlp_w1 = (const float*)d_in[11];
    const float* mlp_b1 = (const float*)d_in[12];
    const float* mlp_w2 = (const float*)d_in[13];
    const float* mlp_b2 = (const float*)d_in[14];
    float* h_out = (float*)d_out;

    char* wsB = (char*)d_ws;
    size_t off = 0;
    auto alloc = [&](size_t bytes) -> void* {
        void* p = (void*)(wsB + off);
        off = (off + bytes + 255) & ~(size_t)255;
        return p;
    };
    float* dinv = (float*)alloc((size_t)NN * 4);
    int* deg = (int*)alloc((size_t)NN * 4);
    int* cursor = (int*)alloc((size_t)NN * 4);
    int* rowptr = (int*)alloc((size_t)(NN + 1) * 4);
    int* bsum = (int*)alloc(128 * 4);
    int* boff = (int*)alloc(128 * 4);
    int* col = (int*)alloc((size_t)EE * 4);
    int* gptr = (int*)alloc((size_t)(GG + 1) * 4);
    float* c1t = (float*)alloc((size_t)GG * HH * 4);
    float* c0t = (float*)alloc((size_t)GG * HH * 4);
    unsigned short* wb =
        (unsigned short*)alloc((size_t)(LL * (HH * HH + MM * HH + HH * MM)) * 2);
    unsigned short* cwb = wb;
    unsigned short* w1b = wb + (size_t)LL * HH * HH;
    unsigned short* w2b = w1b + (size_t)LL * MM * HH;
    unsigned short* hb = (unsigned short*)alloc((size_t)NN * HH * 2);    // bf16 residual
    unsigned short* ybuf = (unsigned short*)alloc((size_t)NN * HH * 2);  // y (conv out)
    unsigned short* aggb = (unsigned short*)alloc((size_t)NN * HH * 2);  // agg bf16

    hipMemsetAsync(deg, 0, (size_t)NN * 4, stream);
    hipMemsetAsync(cursor, 0, (size_t)NN * 4, stream);

    k_embed<<<(NN * 32 + 255) / 256, 256, 0, stream>>>(x, z_embed, extra_w, extra_b, hb);
    {
        int n1 = LL * HH * HH, n2 = LL * MM * HH, n3 = LL * HH * MM;
        int nt = n1 + n2 + n3;
        k_f2bf3<<<(nt + 255) / 256, 256, 0, stream>>>(conv_w, cwb, n1, mlp_w1, w1b, n2,
                                                      mlp_w2, w2b, n3);
    }
    k_degree_p<<<1024, 256, 0, stream>>>(ei + EE, deg);
    k_dinv<<<(NN + 255) / 256, 256, 0, stream>>>(deg, dinv);
    k_scan1<<<SCAN_NB, 256, 0, stream>>>(deg, bsum);
    k_scan2<<<1, 128, 0, stream>>>(bsum, boff);
    k_scan3<<<SCAN_NB, 256, 0, stream>>>(deg, boff, rowptr);
    k_fill_p<<<1024, 256, 0, stream>>>(ei, rowptr, cursor, col);
    k_gptr<<<(NN + 255) / 256, 256, 0, stream>>>(batch, gptr);

    int gconv = (NN + 127) / 128;
    int gmega = (NN + 63) / 64;
    k_conv<<<gconv, 256, 0, stream>>>(hb, cwb, dinv, ybuf);
    for (int i = 0; i < LL; ++i) {
        k_agg<<<(NN + 3) / 4, 256, 0, stream>>>(ybuf, rowptr, col, dinv,
                                                conv_b + (size_t)i * HH, aggb);
        k_stats<<<GG, 512, 0, stream>>>(aggb, gptr, mean_scale + (size_t)i * HH,
                                        gamma + (size_t)i * HH, beta + (size_t)i * HH, c1t,
                                        c0t);
        k_mega<<<gmega, 512, 0, stream>>>(
            aggb, batch, c1t, c0t, w1b + (size_t)i * MM * HH, mlp_b1 + (size_t)i * MM,
            w2b + (size_t)i * HH * MM, mlp_b2 + (size_t)i * HH,
            cwb + (size_t)(i + 1 < LL ? i + 1 : 0) * HH * HH, dinv, hb, h_out, ybuf,
            i == LL - 1 ? 1 : 0, i < LL - 1 ? 1 : 0);
    }
}

// Round 10
// 1346.059 us; speedup vs baseline: 1.2624x; 1.2624x over previous
//
#include <hip/hip_runtime.h>

#define NN 100000
#define EE 1600000
#define HH 128
#define MM 256
#define LL 6
#define GG 512
#define SCAN_NB ((NN + 1023) / 1024)

typedef __attribute__((ext_vector_type(8))) short short8;
typedef __attribute__((ext_vector_type(4))) float floatx4;

__device__ __forceinline__ float swishf(float v) {
    return v / (1.0f + __expf(-v));
}

__device__ __forceinline__ unsigned short f2bf(float f) {
    unsigned u = __builtin_bit_cast(unsigned, f);
    unsigned r = u + 0x7FFFu + ((u >> 16) & 1u);
    return (unsigned short)(r >> 16);
}

__device__ __forceinline__ float bf2f(unsigned short u) {
    return __builtin_bit_cast(float, (unsigned)u << 16);
}

__device__ __forceinline__ float2 bf2f2(unsigned u) {
    float2 r;
    r.x = __builtin_bit_cast(float, u << 16);
    r.y = __builtin_bit_cast(float, u & 0xFFFF0000u);
    return r;
}

__device__ __forceinline__ void unpack8(uint4 v, float* a) {
    float2 p0 = bf2f2(v.x), p1 = bf2f2(v.y), p2 = bf2f2(v.z), p3 = bf2f2(v.w);
    a[0] = p0.x; a[1] = p0.y; a[2] = p1.x; a[3] = p1.y;
    a[4] = p2.x; a[5] = p2.y; a[6] = p3.x; a[7] = p3.y;
}

__device__ __forceinline__ uint4 pack8(const float* o) {
    uint4 pk;
    pk.x = (unsigned)f2bf(o[0]) | ((unsigned)f2bf(o[1]) << 16);
    pk.y = (unsigned)f2bf(o[2]) | ((unsigned)f2bf(o[3]) << 16);
    pk.z = (unsigned)f2bf(o[4]) | ((unsigned)f2bf(o[5]) << 16);
    pk.w = (unsigned)f2bf(o[6]) | ((unsigned)f2bf(o[7]) << 16);
    return pk;
}

__device__ __forceinline__ uint2 pack4(const float* o) {
    uint2 pk;
    pk.x = (unsigned)f2bf(o[0]) | ((unsigned)f2bf(o[1]) << 16);
    pk.y = (unsigned)f2bf(o[2]) | ((unsigned)f2bf(o[3]) << 16);
    return pk;
}

// h[n,c] (row-major bf16) = z_embed[z[n],c] + x[:,1:]@ew^T + eb
__global__ void k_embed(const float* __restrict__ x, const float* __restrict__ z_embed,
                        const float* __restrict__ ew, const float* __restrict__ eb,
                        unsigned short* __restrict__ hb) {
    int idx = blockIdx.x * blockDim.x + threadIdx.x;
    if (idx >= NN * 32) return;
    int n = idx >> 5;
    int c0 = (idx & 31) << 2;
    const float* xr = x + (size_t)n * 4;
    int z = (int)xr[0];
    float x1 = xr[1], x2 = xr[2], x3 = xr[3];
    const float* ze = z_embed + (size_t)z * HH + c0;
    float o[4];
#pragma unroll
    for (int j = 0; j < 4; ++j) {
        int c = c0 + j;
        o[j] = ze[j] + x1 * ew[c * 3 + 0] + x2 * ew[c * 3 + 1] + x3 * ew[c * 3 + 2] + eb[c];
    }
    *(uint2*)(hb + (size_t)n * HH + c0) = pack4(o);
}

__global__ void k_f2bf3(const float* __restrict__ s1, unsigned short* __restrict__ d1, int n1,
                        const float* __restrict__ s2, unsigned short* __restrict__ d2, int n2,
                        const float* __restrict__ s3, unsigned short* __restrict__ d3, int n3) {
    int i = blockIdx.x * blockDim.x + threadIdx.x;
    if (i < n1) {
        d1[i] = f2bf(s1[i]);
    } else if (i < n1 + n2) {
        d2[i - n1] = f2bf(s2[i - n1]);
    } else if (i < n1 + n2 + n3) {
        d3[i - n1 - n2] = f2bf(s3[i - n1 - n2]);
    }
}

__global__ __launch_bounds__(256) void k_degree_p(const int* __restrict__ dst,
                                                  int* __restrict__ deg) {
    int part = blockIdx.x & 7;
    int blk = blockIdx.x >> 3;
    int nb = gridDim.x >> 3;
    int lo = (int)((long long)part * NN / 8);
    int hi = (int)((long long)(part + 1) * NN / 8);
    for (int e = blk * 256 + threadIdx.x; e < EE; e += nb * 256) {
        int d = dst[e];
        if (d >= lo && d < hi) atomicAdd(&deg[d], 1);
    }
}

__global__ void k_dinv(const int* __restrict__ deg, float* __restrict__ dinv) {
    int n = blockIdx.x * blockDim.x + threadIdx.x;
    if (n < NN) dinv[n] = rsqrtf((float)(deg[n] + 1));
}

__global__ void k_scan1(const int* __restrict__ deg, int* __restrict__ bsum) {
    __shared__ int sd[256];
    int t = threadIdx.x;
    int base = blockIdx.x * 1024 + t * 4;
    int s = 0;
#pragma unroll
    for (int j = 0; j < 4; ++j) {
        int i = base + j;
        if (i < NN) s += deg[i];
    }
    sd[t] = s;
    __syncthreads();
    for (int off = 128; off > 0; off >>= 1) {
        if (t < off) sd[t] += sd[t + off];
        __syncthreads();
    }
    if (t == 0) bsum[blockIdx.x] = sd[0];
}

__global__ void k_scan2(const int* __restrict__ bsum, int* __restrict__ boff) {
    __shared__ int sd[128];
    int t = threadIdx.x;
    int v = (t < SCAN_NB) ? bsum[t] : 0;
    sd[t] = v;
    __syncthreads();
    for (int off = 1; off < 128; off <<= 1) {
        int u = (t >= off) ? sd[t - off] : 0;
        __syncthreads();
        sd[t] += u;
        __syncthreads();
    }
    boff[t] = sd[t] - v;  // exclusive
}

__global__ void k_scan3(const int* __restrict__ deg, const int* __restrict__ boff,
                        int* __restrict__ rowptr) {
    __shared__ int sd[256];
    int t = threadIdx.x;
    int base = blockIdx.x * 1024 + t * 4;
    int v[4];
    int s = 0;
#pragma unroll
    for (int j = 0; j < 4; ++j) {
        int i = base + j;
        v[j] = (i < NN) ? deg[i] : 0;
        s += v[j];
    }
    sd[t] = s;
    __syncthreads();
    for (int off = 1; off < 256; off <<= 1) {
        int u = (t >= off) ? sd[t - off] : 0;
        __syncthreads();
        sd[t] += u;
        __syncthreads();
    }
    int run = boff[blockIdx.x] + sd[t] - s;
#pragma unroll
    for (int j = 0; j < 4; ++j) {
        int i = base + j;
        if (i < NN) rowptr[i] = run;
        if (i == NN - 1) rowptr[NN] = run + v[j];
        run += v[j];
    }
}

__global__ __launch_bounds__(256) void k_fill_p(const int* __restrict__ ei,
                                                const int* __restrict__ rowptr,
                                                int* __restrict__ cursor,
                                                int* __restrict__ col) {
    int part = blockIdx.x & 7;
    int blk = blockIdx.x >> 3;
    int nb = gridDim.x >> 3;
    int lo = (int)((long long)part * NN / 8);
    int hi = (int)((long long)(part + 1) * NN / 8);
    for (int e = blk * 256 + threadIdx.x; e < EE; e += nb * 256) {
        int d = ei[EE + e];
        if (d >= lo && d < hi) {
            int p = atomicAdd(&cursor[d], 1);
            col[rowptr[d] + p] = ei[e];
        }
    }
}

__global__ void k_gptr(const int* __restrict__ batch, int* __restrict__ gptr) {
    int n = blockIdx.x * blockDim.x + threadIdx.x;
    if (n >= NN) return;
    int b = batch[n];
    int pb = (n == 0) ? -1 : batch[n - 1];
    for (int g = pb + 1; g <= b; ++g) gptr[g] = n;
    if (n == NN - 1) {
        for (int g = b + 1; g <= GG; ++g) gptr[g] = NN;
    }
}

// Conv GEMM (layer 0 only): y = bf16((h @ Wc^T) * dinv[row]).
__global__ __launch_bounds__(256) void k_conv(const unsigned short* __restrict__ A,
                                              const unsigned short* __restrict__ B,
                                              const float* __restrict__ dinv,
                                              unsigned short* __restrict__ Cb) {
    __shared__ unsigned short Bs[128][HH + 8];
    const int tid = threadIdx.x;
    const int wave = tid >> 6;
    const int lane = tid & 63;
    const int quad = lane >> 4;
    const int l16 = lane & 15;
    const int wr = (wave & 1) << 6;
    const int wc = (wave >> 1) << 6;
    const int rowBase = blockIdx.x * 128;

    for (int i = tid; i < 128 * (HH / 8); i += 256) {
        int r = i / (HH / 8);
        int kk = (i % (HH / 8)) * 8;
        int rho = (r & 64) | ((r & 3) << 4) | ((r >> 2) & 15);
        *(uint4*)(&Bs[rho][kk]) = *(const uint4*)(B + (size_t)r * HH + kk);
    }

    floatx4 acc[4][4];
    const floatx4 zed = {0.f, 0.f, 0.f, 0.f};
#pragma unroll
    for (int i = 0; i < 4; ++i)
#pragma unroll
        for (int j = 0; j < 4; ++j) acc[i][j] = zed;

    int ar[4];
#pragma unroll
    for (int i = 0; i < 4; ++i) {
        int r = rowBase + wr + (i << 4) + l16;
        ar[i] = r < NN ? r : NN - 1;
    }

    __syncthreads();

#pragma unroll
    for (int ks = 0; ks < HH / 32; ++ks) {
        int k = (ks << 5) + (quad << 3);
        short8 a[4], b[4];
#pragma unroll
        for (int i = 0; i < 4; ++i) a[i] = *(const short8*)(A + (size_t)ar[i] * HH + k);
#pragma unroll
        for (int j = 0; j < 4; ++j) b[j] = *(const short8*)(&Bs[wc + (j << 4) + l16][k]);
#pragma unroll
        for (int i = 0; i < 4; ++i)
#pragma unroll
            for (int j = 0; j < 4; ++j)
                acc[i][j] =
                    __builtin_amdgcn_mfma_f32_16x16x32_bf16(a[i], b[j], acc[i][j], 0, 0, 0);
    }

    const int c0 = wc + (l16 << 2);
#pragma unroll
    for (int i = 0; i < 4; ++i) {
        int rb = rowBase + wr + (i << 4) + (quad << 2);
#pragma unroll
        for (int reg = 0; reg < 4; ++reg) {
            int r = rb + reg;
            if (r < NN) {
                float dv = dinv[r];
                float o[4];
#pragma unroll
                for (int j = 0; j < 4; ++j) o[j] = acc[i][j][reg] * dv;
                *(uint2*)(Cb + (size_t)r * HH + c0) = pack4(o);
            }
        }
    }
}

// Wide-load gather (row-major): wave = 1 node; 16 lanes x 16 B cover the 256 B row.
__global__ __launch_bounds__(256) void k_agg(const unsigned short* __restrict__ y,
                                             const int* __restrict__ rowptr,
                                             const int* __restrict__ col,
                                             const float* __restrict__ dinv,
                                             const float* __restrict__ cb,
                                             unsigned short* __restrict__ agg) {
    int w = threadIdx.x >> 6;
    int lane = threadIdx.x & 63;
    int d = blockIdx.x * 4 + w;
    if (d >= NN) return;
    int grp = lane >> 4;
    int l16 = lane & 15;
    const uint4* yv = (const uint4*)y;
    float acc[8];
#pragma unroll
    for (int j = 0; j < 8; ++j) acc[j] = 0.f;
    if (grp == 0) {
        uint4 v = yv[(size_t)d * 16 + l16];
        unpack8(v, acc);
    }
    int beg = rowptr[d];
    int end = rowptr[d + 1];
    for (int e = beg + grp; e < end; e += 4) {
        int s = col[e];
        uint4 v = yv[(size_t)s * 16 + l16];
        float b0[8];
        unpack8(v, b0);
#pragma unroll
        for (int k = 0; k < 8; ++k) acc[k] += b0[k];
    }
#pragma unroll
    for (int j = 0; j < 8; ++j) {
        acc[j] += __shfl_xor(acc[j], 16, 64);
        acc[j] += __shfl_xor(acc[j], 32, 64);
    }
    if (grp == 0) {
        float dv = dinv[d];
        float4 c0 = *(const float4*)(cb + l16 * 8);
        float4 c1 = *(const float4*)(cb + l16 * 8 + 4);
        float o[8];
        o[0] = acc[0] * dv + c0.x; o[1] = acc[1] * dv + c0.y;
        o[2] = acc[2] * dv + c0.z; o[3] = acc[3] * dv + c0.w;
        o[4] = acc[4] * dv + c1.x; o[5] = acc[5] * dv + c1.y;
        o[6] = acc[6] * dv + c1.z; o[7] = acc[7] * dv + c1.w;
        *(uint4*)(agg + (size_t)d * HH + l16 * 8) = pack8(o);
    }
}

// per-graph stats -> affine coeffs: c1 = gamma*rstd, c0 = beta - c1*ms*mean
__global__ __launch_bounds__(512) void k_stats(const unsigned short* __restrict__ agg,
                                               const int* __restrict__ gptr,
                                               const float* __restrict__ ms,
                                               const float* __restrict__ gamma,
                                               const float* __restrict__ beta,
                                               float* __restrict__ c1,
                                               float* __restrict__ c0) {
    __shared__ float s1[512];
    __shared__ float s2[512];
    int g = blockIdx.x;
    int t = threadIdx.x;
    int c = t & 127;
    int part = t >> 7;
    int beg = gptr[g];
    int end = gptr[g + 1];
    float S1 = 0.f, S2 = 0.f;
    for (int n = beg + part; n < end; n += 4) {
        float v = bf2f(agg[(size_t)n * HH + c]);
        S1 += v;
        S2 += v * v;
    }
    s1[t] = S1;
    s2[t] = S2;
    __syncthreads();
    if (part == 0) {
        S1 = (s1[c] + s1[c + 128]) + (s1[c + 256] + s1[c + 384]);
        S2 = (s2[c] + s2[c + 128]) + (s2[c + 256] + s2[c + 384]);
        int cnt = end - beg;
        float inv = 1.0f / (float)(cnt > 0 ? cnt : 1);
        float m = S1 * inv;
        float msc = ms[c];
        float var = S2 * inv - msc * (2.0f - msc) * m * m;
        float rstd = rsqrtf(var + 1e-5f);
        float c1v = gamma[c] * rstd;
        c1[g * HH + c] = c1v;
        c0[g * HH + c] = beta[c] - c1v * msc * m;
    }
}

// Mega layer kernel v3: 256 threads, 64 rows, 4 waves.
// Phase 0: ha = swish(c1*agg + c0) -> LDS ha_s[64][136].
// Phase A: wave owns 64 t-cols, ALL 64 rows: acc1[4][4]; A from LDS, B (W1) from L2;
//          B-loads/MFMA = 0.25. t -> LDS ts[64][264].
// Phase B: wave = 32 rows x 64 out-cols: acc2[2][4]; h' = swish(t@W2^T+b2)+res -> hb
//          (+h_out last layer) and back into ha_s (pitch 136) for phase C.
// Phase C (doConv): y_next = bf16((h'@Wc^T)*dinv).
__global__ __launch_bounds__(256) void k_mega(const unsigned short* __restrict__ agg,
                                              const int* __restrict__ batch,
                                              const float* __restrict__ c1,
                                              const float* __restrict__ c0,
                                              const unsigned short* __restrict__ W1,
                                              const float* __restrict__ b1,
                                              const unsigned short* __restrict__ W2,
                                              const float* __restrict__ b2,
                                              const unsigned short* __restrict__ Wc,
                                              const float* __restrict__ dinv,
                                              unsigned short* __restrict__ hb,
                                              float* __restrict__ h_out,
                                              unsigned short* __restrict__ y_out, int writeF,
                                              int doConv) {
    __shared__ unsigned short ha_s[64 * 136];  // ha, then h' (pitch 136)
    __shared__ unsigned short ts[64 * 264];    // t (pitch 264)
    const int tid = threadIdx.x;
    const int wave = tid >> 6;
    const int lane = tid & 63;
    const int quad = lane >> 4;
    const int l16 = lane & 15;
    const int rowBase = blockIdx.x * 64;
    const floatx4 zed = {0.f, 0.f, 0.f, 0.f};

    // ---- phase 0: normswish -> ha_s ----
    {
        int lr = tid >> 2;           // 0..63
        int coff = (tid & 3) << 5;   // 0,32,64,96
        int r = rowBase + lr;
        if (r >= NN) r = NN - 1;
        int g = batch[r];
        const float* c1p = c1 + g * HH + coff;
        const float* c0p = c0 + g * HH + coff;
#pragma unroll
        for (int q = 0; q < 4; ++q) {
            uint4 raw = *(const uint4*)(agg + (size_t)r * HH + coff + (q << 3));
            float v[8];
            unpack8(raw, v);
            float4 ca = *(const float4*)(c1p + (q << 3));
            float4 cb4 = *(const float4*)(c1p + (q << 3) + 4);
            float4 da = *(const float4*)(c0p + (q << 3));
            float4 db = *(const float4*)(c0p + (q << 3) + 4);
            float cc1[8] = {ca.x, ca.y, ca.z, ca.w, cb4.x, cb4.y, cb4.z, cb4.w};
            float cc0[8] = {da.x, da.y, da.z, da.w, db.x, db.y, db.z, db.w};
            float o[8];
#pragma unroll
            for (int j = 0; j < 8; ++j) o[j] = swishf(cc1[j] * v[j] + cc0[j]);
            *(uint4*)(&ha_s[lr * 136 + coff + (q << 3)]) = pack8(o);
        }
    }
    __syncthreads();

    // ---- phase A: t = swish(ha @ W1^T + b1) ----
    {
        const int wca = wave << 6;  // 64 t-cols per wave
        floatx4 acc1[4][4];
#pragma unroll
        for (int i = 0; i < 4; ++i)
#pragma unroll
            for (int j = 0; j < 4; ++j) acc1[i][j] = zed;
#pragma unroll
        for (int ks = 0; ks < 4; ++ks) {
            int k = (ks << 5) + (quad << 3);
            short8 a[4], b[4];
#pragma unroll
            for (int i = 0; i < 4; ++i)
                a[i] = *(const short8*)(&ha_s[((i << 4) + l16) * 136 + k]);
#pragma unroll
            for (int j = 0; j < 4; ++j)
                b[j] = *(const short8*)(W1 + (size_t)(wca + (l16 << 2) + j) * HH + k);
#pragma unroll
            for (int i = 0; i < 4; ++i)
#pragma unroll
                for (int j = 0; j < 4; ++j)
                    acc1[i][j] =
                        __builtin_amdgcn_mfma_f32_16x16x32_bf16(a[i], b[j], acc1[i][j], 0, 0, 0);
        }
        const int ct = wca + (l16 << 2);
        float4 b4 = *(const float4*)(b1 + ct);
        float bv[4] = {b4.x, b4.y, b4.z, b4.w};
#pragma unroll
        for (int i = 0; i < 4; ++i) {
#pragma unroll
            for (int reg = 0; reg < 4; ++reg) {
                int lr = (i << 4) + (quad << 2) + reg;
                float o[4];
#pragma unroll
                for (int j = 0; j < 4; ++j) o[j] = swishf(acc1[i][j][reg] + bv[j]);
                *(uint2*)(&ts[lr * 264 + ct]) = pack4(o);
            }
        }
    }
    __syncthreads();

    // ---- phase B: h' = swish(t @ W2^T + b2) + res ----
    const int wrb = (wave & 1) << 5;   // 0/32
    const int wcb = (wave >> 1) << 6;  // 0/64
    const int co = wcb + (l16 << 2);
    {
        floatx4 acc2[2][4];
#pragma unroll
        for (int i = 0; i < 2; ++i)
#pragma unroll
            for (int j = 0; j < 4; ++j) acc2[i][j] = zed;
#pragma unroll
        for (int ks = 0; ks < 8; ++ks) {
            int k = (ks << 5) + (quad << 3);
            short8 a[2], b[4];
#pragma unroll
            for (int i = 0; i < 2; ++i)
                a[i] = *(const short8*)(&ts[(wrb + (i << 4) + l16) * 264 + k]);
#pragma unroll
            for (int j = 0; j < 4; ++j)
                b[j] = *(const short8*)(W2 + (size_t)(wcb + (l16 << 2) + j) * MM + k);
#pragma unroll
            for (int i = 0; i < 2; ++i)
#pragma unroll
                for (int j = 0; j < 4; ++j)
                    acc2[i][j] =
                        __builtin_amdgcn_mfma_f32_16x16x32_bf16(a[i], b[j], acc2[i][j], 0, 0, 0);
        }
        float4 b4 = *(const float4*)(b2 + co);
        float bv[4] = {b4.x, b4.y, b4.z, b4.w};
#pragma unroll
        for (int i = 0; i < 2; ++i) {
#pragma unroll
            for (int reg = 0; reg < 4; ++reg) {
                int lr = wrb + (i << 4) + (quad << 2) + reg;
                int r = rowBase + lr;
                if (r < NN) {
                    uint2 rv = *(const uint2*)(hb + (size_t)r * HH + co);
                    float2 r01 = bf2f2(rv.x), r23 = bf2f2(rv.y);
                    float o[4];
                    o[0] = swishf(acc2[i][0][reg] + bv[0]) + r01.x;
                    o[1] = swishf(acc2[i][1][reg] + bv[1]) + r01.y;
                    o[2] = swishf(acc2[i][2][reg] + bv[2]) + r23.x;
                    o[3] = swishf(acc2[i][3][reg] + bv[3]) + r23.y;
                    uint2 pk = pack4(o);
                    *(uint2*)(hb + (size_t)r * HH + co) = pk;
                    if (writeF)
                        *(float4*)(h_out + (size_t)r * HH + co) =
                            make_float4(o[0], o[1], o[2], o[3]);
                    *(uint2*)(&ha_s[lr * 136 + co]) = pk;
                } else {
                    *(uint2*)(&ha_s[lr * 136 + co]) = make_uint2(0u, 0u);
                }
            }
        }
    }

    // ---- phase C: y_next = bf16((h' @ Wc^T) * dinv) ----
    if (doConv) {
        __syncthreads();
        floatx4 acc3[2][4];
#pragma unroll
        for (int i = 0; i < 2; ++i)
#pragma unroll
            for (int j = 0; j < 4; ++j) acc3[i][j] = zed;
#pragma unroll
        for (int ks = 0; ks < 4; ++ks) {
            int k = (ks << 5) + (quad << 3);
            short8 a[2], b[4];
#pragma unroll
            for (int i = 0; i < 2; ++i)
                a[i] = *(const short8*)(&ha_s[(wrb + (i << 4) + l16) * 136 + k]);
#pragma unroll
            for (int j = 0; j < 4; ++j)
                b[j] = *(const short8*)(Wc + (size_t)(wcb + (l16 << 2) + j) * HH + k);
#pragma unroll
            for (int i = 0; i < 2; ++i)
#pragma unroll
                for (int j = 0; j < 4; ++j)
                    acc3[i][j] =
                        __builtin_amdgcn_mfma_f32_16x16x32_bf16(a[i], b[j], acc3[i][j], 0, 0, 0);
        }
#pragma unroll
        for (int i = 0; i < 2; ++i) {
#pragma unroll
            for (int reg = 0; reg < 4; ++reg) {
                int r = rowBase + wrb + (i << 4) + (quad << 2) + reg;
                if (r < NN) {
                    float dv = dinv[r];
                    float o[4];
#pragma unroll
                    for (int j = 0; j < 4; ++j) o[j] = acc3[i][j][reg] * dv;
                    *(uint2*)(y_out + (size_t)r * HH + co) = pack4(o);
                }
            }
        }
    }
}

extern "C" void kernel_launch(void* const* d_in, const int* in_sizes, int n_in,
                              void* d_out, int out_size, void* d_ws, size_t ws_size,
                              hipStream_t stream) {
    const float* x = (const float*)d_in[0];
    const int* ei = (const int*)d_in[1];
    const int* batch = (const int*)d_in[2];
    const float* z_embed = (const float*)d_in[3];
    const float* extra_w = (const float*)d_in[4];
    const float* extra_b = (const float*)d_in[5];
    const float* conv_w = (const float*)d_in[6];
    const float* conv_b = (const float*)d_in[7];
    const float* gamma = (const float*)d_in[8];
    const float* beta = (const float*)d_in[9];
    const float* mean_scale = (const float*)d_in[10];
    const float* mlp_w1 = (const float*)d_in[11];
    const float* mlp_b1 = (const float*)d_in[12];
    const float* mlp_w2 = (const float*)d_in[13];
    const float* mlp_b2 = (const float*)d_in[14];
    float* h_out = (float*)d_out;

    char* wsB = (char*)d_ws;
    size_t off = 0;
    auto alloc = [&](size_t bytes) -> void* {
        void* p = (void*)(wsB + off);
        off = (off + bytes + 255) & ~(size_t)255;
        return p;
    };
    float* dinv = (float*)alloc((size_t)NN * 4);
    int* deg = (int*)alloc((size_t)NN * 4);
    int* cursor = (int*)alloc((size_t)NN * 4);
    int* rowptr = (int*)alloc((size_t)(NN + 1) * 4);
    int* bsum = (int*)alloc(128 * 4);
    int* boff = (int*)alloc(128 * 4);
    int* col = (int*)alloc((size_t)EE * 4);
    int* gptr = (int*)alloc((size_t)(GG + 1) * 4);
    float* c1t = (float*)alloc((size_t)GG * HH * 4);
    float* c0t = (float*)alloc((size_t)GG * HH * 4);
    unsigned short* wb =
        (unsigned short*)alloc((size_t)(LL * (HH * HH + MM * HH + HH * MM)) * 2);
    unsigned short* cwb = wb;
    unsigned short* w1b = wb + (size_t)LL * HH * HH;
    unsigned short* w2b = w1b + (size_t)LL * MM * HH;
    unsigned short* hb = (unsigned short*)alloc((size_t)NN * HH * 2);    // bf16 residual
    unsigned short* ybuf = (unsigned short*)alloc((size_t)NN * HH * 2);  // y (conv out)
    unsigned short* aggb = (unsigned short*)alloc((size_t)NN * HH * 2);  // agg bf16

    hipMemsetAsync(deg, 0, (size_t)NN * 4, stream);
    hipMemsetAsync(cursor, 0, (size_t)NN * 4, stream);

    k_embed<<<(NN * 32 + 255) / 256, 256, 0, stream>>>(x, z_embed, extra_w, extra_b, hb);
    {
        int n1 = LL * HH * HH, n2 = LL * MM * HH, n3 = LL * HH * MM;
        int nt = n1 + n2 + n3;
        k_f2bf3<<<(nt + 255) / 256, 256, 0, stream>>>(conv_w, cwb, n1, mlp_w1, w1b, n2,
                                                      mlp_w2, w2b, n3);
    }
    k_degree_p<<<1024, 256, 0, stream>>>(ei + EE, deg);
    k_dinv<<<(NN + 255) / 256, 256, 0, stream>>>(deg, dinv);
    k_scan1<<<SCAN_NB, 256, 0, stream>>>(deg, bsum);
    k_scan2<<<1, 128, 0, stream>>>(bsum, boff);
    k_scan3<<<SCAN_NB, 256, 0, stream>>>(deg, boff, rowptr);
    k_fill_p<<<1024, 256, 0, stream>>>(ei, rowptr, cursor, col);
    k_gptr<<<(NN + 255) / 256, 256, 0, stream>>>(batch, gptr);

    int gconv = (NN + 127) / 128;
    int gmega = (NN + 63) / 64;
    k_conv<<<gconv, 256, 0, stream>>>(hb, cwb, dinv, ybuf);
    for (int i = 0; i < LL; ++i) {
        k_agg<<<(NN + 3) / 4, 256, 0, stream>>>(ybuf, rowptr, col, dinv,
                                                conv_b + (size_t)i * HH, aggb);
        k_stats<<<GG, 512, 0, stream>>>(aggb, gptr, mean_scale + (size_t)i * HH,
                                        gamma + (size_t)i * HH, beta + (size_t)i * HH, c1t,
                                        c0t);
        k_mega<<<gmega, 256, 0, stream>>>(
            aggb, batch, c1t, c0t, w1b + (size_t)i * MM * HH, mlp_b1 + (size_t)i * MM,
            w2b + (size_t)i * HH * MM, mlp_b2 + (size_t)i * HH,
            cwb + (size_t)(i + 1 < LL ? i + 1 : 0) * HH * HH, dinv, hb, h_out, ybuf,
            i == LL - 1 ? 1 : 0, i < LL - 1 ? 1 : 0);
    }
}

// Round 11
// 1334.290 us; speedup vs baseline: 1.2735x; 1.0088x over previous
//
#include <hip/hip_runtime.h>

#define NN 100000
#define EE 1600000
#define HH 128
#define MM 256
#define LL 6
#define GG 512
#define SCAN_NB ((NN + 1023) / 1024)

typedef __attribute__((ext_vector_type(8))) short short8;
typedef __attribute__((ext_vector_type(4))) float floatx4;

__device__ __forceinline__ float swishf(float v) {
    return v / (1.0f + __expf(-v));
}

__device__ __forceinline__ unsigned short f2bf(float f) {
    unsigned u = __builtin_bit_cast(unsigned, f);
    unsigned r = u + 0x7FFFu + ((u >> 16) & 1u);
    return (unsigned short)(r >> 16);
}

__device__ __forceinline__ float bf2f(unsigned short u) {
    return __builtin_bit_cast(float, (unsigned)u << 16);
}

__device__ __forceinline__ float2 bf2f2(unsigned u) {
    float2 r;
    r.x = __builtin_bit_cast(float, u << 16);
    r.y = __builtin_bit_cast(float, u & 0xFFFF0000u);
    return r;
}

__device__ __forceinline__ void unpack8(uint4 v, float* a) {
    float2 p0 = bf2f2(v.x), p1 = bf2f2(v.y), p2 = bf2f2(v.z), p3 = bf2f2(v.w);
    a[0] = p0.x; a[1] = p0.y; a[2] = p1.x; a[3] = p1.y;
    a[4] = p2.x; a[5] = p2.y; a[6] = p3.x; a[7] = p3.y;
}

__device__ __forceinline__ uint4 pack8(const float* o) {
    uint4 pk;
    pk.x = (unsigned)f2bf(o[0]) | ((unsigned)f2bf(o[1]) << 16);
    pk.y = (unsigned)f2bf(o[2]) | ((unsigned)f2bf(o[3]) << 16);
    pk.z = (unsigned)f2bf(o[4]) | ((unsigned)f2bf(o[5]) << 16);
    pk.w = (unsigned)f2bf(o[6]) | ((unsigned)f2bf(o[7]) << 16);
    return pk;
}

__device__ __forceinline__ uint2 pack4(const float* o) {
    uint2 pk;
    pk.x = (unsigned)f2bf(o[0]) | ((unsigned)f2bf(o[1]) << 16);
    pk.y = (unsigned)f2bf(o[2]) | ((unsigned)f2bf(o[3]) << 16);
    return pk;
}

// h[n,c] (row-major bf16) = z_embed[z[n],c] + x[:,1:]@ew^T + eb
__global__ void k_embed(const float* __restrict__ x, const float* __restrict__ z_embed,
                        const float* __restrict__ ew, const float* __restrict__ eb,
                        unsigned short* __restrict__ hb) {
    int idx = blockIdx.x * blockDim.x + threadIdx.x;
    if (idx >= NN * 32) return;
    int n = idx >> 5;
    int c0 = (idx & 31) << 2;
    const float* xr = x + (size_t)n * 4;
    int z = (int)xr[0];
    float x1 = xr[1], x2 = xr[2], x3 = xr[3];
    const float* ze = z_embed + (size_t)z * HH + c0;
    float o[4];
#pragma unroll
    for (int j = 0; j < 4; ++j) {
        int c = c0 + j;
        o[j] = ze[j] + x1 * ew[c * 3 + 0] + x2 * ew[c * 3 + 1] + x3 * ew[c * 3 + 2] + eb[c];
    }
    *(uint2*)(hb + (size_t)n * HH + c0) = pack4(o);
}

__global__ void k_f2bf3(const float* __restrict__ s1, unsigned short* __restrict__ d1, int n1,
                        const float* __restrict__ s2, unsigned short* __restrict__ d2, int n2,
                        const float* __restrict__ s3, unsigned short* __restrict__ d3, int n3) {
    int i = blockIdx.x * blockDim.x + threadIdx.x;
    if (i < n1) {
        d1[i] = f2bf(s1[i]);
    } else if (i < n1 + n2) {
        d2[i - n1] = f2bf(s2[i - n1]);
    } else if (i < n1 + n2 + n3) {
        d3[i - n1 - n2] = f2bf(s3[i - n1 - n2]);
    }
}

__global__ __launch_bounds__(256) void k_degree_p(const int* __restrict__ dst,
                                                  int* __restrict__ deg) {
    int part = blockIdx.x & 7;
    int blk = blockIdx.x >> 3;
    int nb = gridDim.x >> 3;
    int lo = (int)((long long)part * NN / 8);
    int hi = (int)((long long)(part + 1) * NN / 8);
    for (int e = blk * 256 + threadIdx.x; e < EE; e += nb * 256) {
        int d = dst[e];
        if (d >= lo && d < hi) atomicAdd(&deg[d], 1);
    }
}

__global__ void k_dinv(const int* __restrict__ deg, float* __restrict__ dinv) {
    int n = blockIdx.x * blockDim.x + threadIdx.x;
    if (n < NN) dinv[n] = rsqrtf((float)(deg[n] + 1));
}

__global__ void k_scan1(const int* __restrict__ deg, int* __restrict__ bsum) {
    __shared__ int sd[256];
    int t = threadIdx.x;
    int base = blockIdx.x * 1024 + t * 4;
    int s = 0;
#pragma unroll
    for (int j = 0; j < 4; ++j) {
        int i = base + j;
        if (i < NN) s += deg[i];
    }
    sd[t] = s;
    __syncthreads();
    for (int off = 128; off > 0; off >>= 1) {
        if (t < off) sd[t] += sd[t + off];
        __syncthreads();
    }
    if (t == 0) bsum[blockIdx.x] = sd[0];
}

__global__ void k_scan2(const int* __restrict__ bsum, int* __restrict__ boff) {
    __shared__ int sd[128];
    int t = threadIdx.x;
    int v = (t < SCAN_NB) ? bsum[t] : 0;
    sd[t] = v;
    __syncthreads();
    for (int off = 1; off < 128; off <<= 1) {
        int u = (t >= off) ? sd[t - off] : 0;
        __syncthreads();
        sd[t] += u;
        __syncthreads();
    }
    boff[t] = sd[t] - v;  // exclusive
}

__global__ void k_scan3(const int* __restrict__ deg, const int* __restrict__ boff,
                        int* __restrict__ rowptr) {
    __shared__ int sd[256];
    int t = threadIdx.x;
    int base = blockIdx.x * 1024 + t * 4;
    int v[4];
    int s = 0;
#pragma unroll
    for (int j = 0; j < 4; ++j) {
        int i = base + j;
        v[j] = (i < NN) ? deg[i] : 0;
        s += v[j];
    }
    sd[t] = s;
    __syncthreads();
    for (int off = 1; off < 256; off <<= 1) {
        int u = (t >= off) ? sd[t - off] : 0;
        __syncthreads();
        sd[t] += u;
        __syncthreads();
    }
    int run = boff[blockIdx.x] + sd[t] - s;
#pragma unroll
    for (int j = 0; j < 4; ++j) {
        int i = base + j;
        if (i < NN) rowptr[i] = run;
        if (i == NN - 1) rowptr[NN] = run + v[j];
        run += v[j];
    }
}

__global__ __launch_bounds__(256) void k_fill_p(const int* __restrict__ ei,
                                                const int* __restrict__ rowptr,
                                                int* __restrict__ cursor,
                                                int* __restrict__ col) {
    int part = blockIdx.x & 7;
    int blk = blockIdx.x >> 3;
    int nb = gridDim.x >> 3;
    int lo = (int)((long long)part * NN / 8);
    int hi = (int)((long long)(part + 1) * NN / 8);
    for (int e = blk * 256 + threadIdx.x; e < EE; e += nb * 256) {
        int d = ei[EE + e];
        if (d >= lo && d < hi) {
            int p = atomicAdd(&cursor[d], 1);
            col[rowptr[d] + p] = ei[e];
        }
    }
}

__global__ void k_gptr(const int* __restrict__ batch, int* __restrict__ gptr) {
    int n = blockIdx.x * blockDim.x + threadIdx.x;
    if (n >= NN) return;
    int b = batch[n];
    int pb = (n == 0) ? -1 : batch[n - 1];
    for (int g = pb + 1; g <= b; ++g) gptr[g] = n;
    if (n == NN - 1) {
        for (int g = b + 1; g <= GG; ++g) gptr[g] = NN;
    }
}

// Conv GEMM (layer 0 only): y = bf16((h @ Wc^T) * dinv[row]).
__global__ __launch_bounds__(256) void k_conv(const unsigned short* __restrict__ A,
                                              const unsigned short* __restrict__ B,
                                              const float* __restrict__ dinv,
                                              unsigned short* __restrict__ Cb) {
    __shared__ unsigned short Bs[128][HH + 8];
    const int tid = threadIdx.x;
    const int wave = tid >> 6;
    const int lane = tid & 63;
    const int quad = lane >> 4;
    const int l16 = lane & 15;
    const int wr = (wave & 1) << 6;
    const int wc = (wave >> 1) << 6;
    const int rowBase = blockIdx.x * 128;

    for (int i = tid; i < 128 * (HH / 8); i += 256) {
        int r = i / (HH / 8);
        int kk = (i % (HH / 8)) * 8;
        int rho = (r & 64) | ((r & 3) << 4) | ((r >> 2) & 15);
        *(uint4*)(&Bs[rho][kk]) = *(const uint4*)(B + (size_t)r * HH + kk);
    }

    floatx4 acc[4][4];
    const floatx4 zed = {0.f, 0.f, 0.f, 0.f};
#pragma unroll
    for (int i = 0; i < 4; ++i)
#pragma unroll
        for (int j = 0; j < 4; ++j) acc[i][j] = zed;

    int ar[4];
#pragma unroll
    for (int i = 0; i < 4; ++i) {
        int r = rowBase + wr + (i << 4) + l16;
        ar[i] = r < NN ? r : NN - 1;
    }

    __syncthreads();

#pragma unroll
    for (int ks = 0; ks < HH / 32; ++ks) {
        int k = (ks << 5) + (quad << 3);
        short8 a[4], b[4];
#pragma unroll
        for (int i = 0; i < 4; ++i) a[i] = *(const short8*)(A + (size_t)ar[i] * HH + k);
#pragma unroll
        for (int j = 0; j < 4; ++j) b[j] = *(const short8*)(&Bs[wc + (j << 4) + l16][k]);
#pragma unroll
        for (int i = 0; i < 4; ++i)
#pragma unroll
            for (int j = 0; j < 4; ++j)
                acc[i][j] =
                    __builtin_amdgcn_mfma_f32_16x16x32_bf16(a[i], b[j], acc[i][j], 0, 0, 0);
    }

    const int c0 = wc + (l16 << 2);
#pragma unroll
    for (int i = 0; i < 4; ++i) {
        int rb = rowBase + wr + (i << 4) + (quad << 2);
#pragma unroll
        for (int reg = 0; reg < 4; ++reg) {
            int r = rb + reg;
            if (r < NN) {
                float dv = dinv[r];
                float o[4];
#pragma unroll
                for (int j = 0; j < 4; ++j) o[j] = acc[i][j][reg] * dv;
                *(uint2*)(Cb + (size_t)r * HH + c0) = pack4(o);
            }
        }
    }
}

// Wide-load gather + fused per-graph stats accumulation.
// Wave = 1 node; 16 lanes x 16 B cover the 256 B row; butterfly reduce.
// Block (4 nodes) LDS-reduces stats; same-graph fast path -> 256 atomics/block.
__global__ __launch_bounds__(256) void k_agg(const unsigned short* __restrict__ y,
                                             const int* __restrict__ rowptr,
                                             const int* __restrict__ col,
                                             const float* __restrict__ dinv,
                                             const float* __restrict__ cb,
                                             const int* __restrict__ batch,
                                             unsigned short* __restrict__ agg,
                                             float* __restrict__ S1g,
                                             float* __restrict__ S2g) {
    __shared__ float s1s[4][128];
    __shared__ float s2s[4][128];
    __shared__ int sg[4];
    int w = threadIdx.x >> 6;
    int lane = threadIdx.x & 63;
    int d = blockIdx.x * 4 + w;
    bool valid = d < NN;
    int grp = lane >> 4;
    int l16 = lane & 15;
    const uint4* yv = (const uint4*)y;
    float acc[8];
#pragma unroll
    for (int j = 0; j < 8; ++j) acc[j] = 0.f;
    if (grp == 0 && valid) {
        uint4 v = yv[(size_t)d * 16 + l16];
        unpack8(v, acc);
    }
    int beg = 0, end = 0;
    if (valid) {
        beg = rowptr[d];
        end = rowptr[d + 1];
    }
    for (int e = beg + grp; e < end; e += 4) {
        int s = col[e];
        uint4 v = yv[(size_t)s * 16 + l16];
        float b0[8];
        unpack8(v, b0);
#pragma unroll
        for (int k = 0; k < 8; ++k) acc[k] += b0[k];
    }
#pragma unroll
    for (int j = 0; j < 8; ++j) {
        acc[j] += __shfl_xor(acc[j], 16, 64);
        acc[j] += __shfl_xor(acc[j], 32, 64);
    }
    if (grp == 0) {
        if (valid) {
            float dv = dinv[d];
            float4 c0 = *(const float4*)(cb + l16 * 8);
            float4 c1 = *(const float4*)(cb + l16 * 8 + 4);
            float o[8];
            o[0] = acc[0] * dv + c0.x; o[1] = acc[1] * dv + c0.y;
            o[2] = acc[2] * dv + c0.z; o[3] = acc[3] * dv + c0.w;
            o[4] = acc[4] * dv + c1.x; o[5] = acc[5] * dv + c1.y;
            o[6] = acc[6] * dv + c1.z; o[7] = acc[7] * dv + c1.w;
            unsigned short us[8];
#pragma unroll
            for (int j = 0; j < 8; ++j) us[j] = f2bf(o[j]);
            uint4 pk;
            pk.x = (unsigned)us[0] | ((unsigned)us[1] << 16);
            pk.y = (unsigned)us[2] | ((unsigned)us[3] << 16);
            pk.z = (unsigned)us[4] | ((unsigned)us[5] << 16);
            pk.w = (unsigned)us[6] | ((unsigned)us[7] << 16);
            *(uint4*)(agg + (size_t)d * HH + l16 * 8) = pk;
#pragma unroll
            for (int j = 0; j < 8; ++j) {
                float orv = bf2f(us[j]);  // rounded value, matches what consumers read
                s1s[w][l16 * 8 + j] = orv;
                s2s[w][l16 * 8 + j] = orv * orv;
            }
        } else {
#pragma unroll
            for (int j = 0; j < 8; ++j) {
                s1s[w][l16 * 8 + j] = 0.f;
                s2s[w][l16 * 8 + j] = 0.f;
            }
        }
        if (l16 == 0) sg[w] = valid ? batch[d] : -1;
    }
    __syncthreads();
    if (threadIdx.x < 128) {
        int c = threadIdx.x;
        int g0 = sg[0], g1 = sg[1], g2 = sg[2], g3 = sg[3];
        if (g0 >= 0 && g0 == g1 && g0 == g2 && g0 == g3) {
            float a = (s1s[0][c] + s1s[1][c]) + (s1s[2][c] + s1s[3][c]);
            float b = (s2s[0][c] + s2s[1][c]) + (s2s[2][c] + s2s[3][c]);
            atomicAdd(&S1g[g0 * HH + c], a);
            atomicAdd(&S2g[g0 * HH + c], b);
        } else {
            int gs[4] = {g0, g1, g2, g3};
#pragma unroll
            for (int ww = 0; ww < 4; ++ww) {
                if (gs[ww] >= 0) {
                    atomicAdd(&S1g[gs[ww] * HH + c], s1s[ww][c]);
                    atomicAdd(&S2g[gs[ww] * HH + c], s2s[ww][c]);
                }
            }
        }
    }
}

// finalize: c1 = gamma*rstd, c0 = beta - c1*ms*mean; zero S buffers for next layer
__global__ __launch_bounds__(128) void k_finalize(const int* __restrict__ gptr,
                                                  const float* __restrict__ ms,
                                                  const float* __restrict__ gamma,
                                                  const float* __restrict__ beta,
                                                  float* __restrict__ S1g,
                                                  float* __restrict__ S2g,
                                                  float* __restrict__ c1,
                                                  float* __restrict__ c0) {
    int g = blockIdx.x;
    int c = threadIdx.x;
    int cnt = gptr[g + 1] - gptr[g];
    float inv = 1.0f / (float)(cnt > 0 ? cnt : 1);
    float S1 = S1g[g * HH + c];
    float S2 = S2g[g * HH + c];
    float m = S1 * inv;
    float msc = ms[c];
    float var = S2 * inv - msc * (2.0f - msc) * m * m;
    float rstd = rsqrtf(var + 1e-5f);
    float c1v = gamma[c] * rstd;
    c1[g * HH + c] = c1v;
    c0[g * HH + c] = beta[c] - c1v * msc * m;
    S1g[g * HH + c] = 0.f;
    S2g[g * HH + c] = 0.f;
}

// Mega layer kernel: 256 threads, 64 rows, 4 waves, min 3 waves/EU.
// Phase 0: ha = swish(c1*agg + c0) -> LDS ha_s[64][136].
// Phase A: wave owns 64 t-cols, ALL 64 rows: acc1[4][4]; B-loads/MFMA = 0.25.
// Phase B: wave = 32 rows x 64 out-cols; h' -> hb (+h_out last) and ha_s for phase C.
// Phase C (doConv): y_next = bf16((h'@Wc^T)*dinv).
__global__ __launch_bounds__(256, 3) void k_mega(const unsigned short* __restrict__ agg,
                                                 const int* __restrict__ batch,
                                                 const float* __restrict__ c1,
                                                 const float* __restrict__ c0,
                                                 const unsigned short* __restrict__ W1,
                                                 const float* __restrict__ b1,
                                                 const unsigned short* __restrict__ W2,
                                                 const float* __restrict__ b2,
                                                 const unsigned short* __restrict__ Wc,
                                                 const float* __restrict__ dinv,
                                                 unsigned short* __restrict__ hb,
                                                 float* __restrict__ h_out,
                                                 unsigned short* __restrict__ y_out,
                                                 int writeF, int doConv) {
    __shared__ unsigned short ha_s[64 * 136];  // ha, then h' (pitch 136)
    __shared__ unsigned short ts[64 * 264];    // t (pitch 264)
    const int tid = threadIdx.x;
    const int wave = tid >> 6;
    const int lane = tid & 63;
    const int quad = lane >> 4;
    const int l16 = lane & 15;
    const int rowBase = blockIdx.x * 64;
    const floatx4 zed = {0.f, 0.f, 0.f, 0.f};

    // ---- phase 0: normswish -> ha_s ----
    {
        int lr = tid >> 2;           // 0..63
        int coff = (tid & 3) << 5;   // 0,32,64,96
        int r = rowBase + lr;
        if (r >= NN) r = NN - 1;
        int g = batch[r];
        const float* c1p = c1 + g * HH + coff;
        const float* c0p = c0 + g * HH + coff;
#pragma unroll
        for (int q = 0; q < 4; ++q) {
            uint4 raw = *(const uint4*)(agg + (size_t)r * HH + coff + (q << 3));
            float v[8];
            unpack8(raw, v);
            float4 ca = *(const float4*)(c1p + (q << 3));
            float4 cb4 = *(const float4*)(c1p + (q << 3) + 4);
            float4 da = *(const float4*)(c0p + (q << 3));
            float4 db = *(const float4*)(c0p + (q << 3) + 4);
            float cc1[8] = {ca.x, ca.y, ca.z, ca.w, cb4.x, cb4.y, cb4.z, cb4.w};
            float cc0[8] = {da.x, da.y, da.z, da.w, db.x, db.y, db.z, db.w};
            float o[8];
#pragma unroll
            for (int j = 0; j < 8; ++j) o[j] = swishf(cc1[j] * v[j] + cc0[j]);
            *(uint4*)(&ha_s[lr * 136 + coff + (q << 3)]) = pack8(o);
        }
    }
    __syncthreads();

    // ---- phase A: t = swish(ha @ W1^T + b1) ----
    {
        const int wca = wave << 6;  // 64 t-cols per wave
        floatx4 acc1[4][4];
#pragma unroll
        for (int i = 0; i < 4; ++i)
#pragma unroll
            for (int j = 0; j < 4; ++j) acc1[i][j] = zed;
#pragma unroll
        for (int ks = 0; ks < 4; ++ks) {
            int k = (ks << 5) + (quad << 3);
            short8 a[4], b[4];
#pragma unroll
            for (int i = 0; i < 4; ++i)
                a[i] = *(const short8*)(&ha_s[((i << 4) + l16) * 136 + k]);
#pragma unroll
            for (int j = 0; j < 4; ++j)
                b[j] = *(const short8*)(W1 + (size_t)(wca + (l16 << 2) + j) * HH + k);
#pragma unroll
            for (int i = 0; i < 4; ++i)
#pragma unroll
                for (int j = 0; j < 4; ++j)
                    acc1[i][j] =
                        __builtin_amdgcn_mfma_f32_16x16x32_bf16(a[i], b[j], acc1[i][j], 0, 0, 0);
        }
        const int ct = wca + (l16 << 2);
        float4 b4 = *(const float4*)(b1 + ct);
        float bv[4] = {b4.x, b4.y, b4.z, b4.w};
#pragma unroll
        for (int i = 0; i < 4; ++i) {
#pragma unroll
            for (int reg = 0; reg < 4; ++reg) {
                int lr = (i << 4) + (quad << 2) + reg;
                float o[4];
#pragma unroll
                for (int j = 0; j < 4; ++j) o[j] = swishf(acc1[i][j][reg] + bv[j]);
                *(uint2*)(&ts[lr * 264 + ct]) = pack4(o);
            }
        }
    }
    __syncthreads();

    // ---- phase B: h' = swish(t @ W2^T + b2) + res ----
    const int wrb = (wave & 1) << 5;   // 0/32
    const int wcb = (wave >> 1) << 6;  // 0/64
    const int co = wcb + (l16 << 2);
    {
        floatx4 acc2[2][4];
#pragma unroll
        for (int i = 0; i < 2; ++i)
#pragma unroll
            for (int j = 0; j < 4; ++j) acc2[i][j] = zed;
#pragma unroll
        for (int ks = 0; ks < 8; ++ks) {
            int k = (ks << 5) + (quad << 3);
            short8 a[2], b[4];
#pragma unroll
            for (int i = 0; i < 2; ++i)
                a[i] = *(const short8*)(&ts[(wrb + (i << 4) + l16) * 264 + k]);
#pragma unroll
            for (int j = 0; j < 4; ++j)
                b[j] = *(const short8*)(W2 + (size_t)(wcb + (l16 << 2) + j) * MM + k);
#pragma unroll
            for (int i = 0; i < 2; ++i)
#pragma unroll
                for (int j = 0; j < 4; ++j)
                    acc2[i][j] =
                        __builtin_amdgcn_mfma_f32_16x16x32_bf16(a[i], b[j], acc2[i][j], 0, 0, 0);
        }
        float4 b4 = *(const float4*)(b2 + co);
        float bv[4] = {b4.x, b4.y, b4.z, b4.w};
#pragma unroll
        for (int i = 0; i < 2; ++i) {
#pragma unroll
            for (int reg = 0; reg < 4; ++reg) {
                int lr = wrb + (i << 4) + (quad << 2) + reg;
                int r = rowBase + lr;
                if (r < NN) {
                    uint2 rv = *(const uint2*)(hb + (size_t)r * HH + co);
                    float2 r01 = bf2f2(rv.x), r23 = bf2f2(rv.y);
                    float o[4];
                    o[0] = swishf(acc2[i][0][reg] + bv[0]) + r01.x;
                    o[1] = swishf(acc2[i][1][reg] + bv[1]) + r01.y;
                    o[2] = swishf(acc2[i][2][reg] + bv[2]) + r23.x;
                    o[3] = swishf(acc2[i][3][reg] + bv[3]) + r23.y;
                    uint2 pk = pack4(o);
                    *(uint2*)(hb + (size_t)r * HH + co) = pk;
                    if (writeF)
                        *(float4*)(h_out + (size_t)r * HH + co) =
                            make_float4(o[0], o[1], o[2], o[3]);
                    *(uint2*)(&ha_s[lr * 136 + co]) = pk;
                } else {
                    *(uint2*)(&ha_s[lr * 136 + co]) = make_uint2(0u, 0u);
                }
            }
        }
    }

    // ---- phase C: y_next = bf16((h' @ Wc^T) * dinv) ----
    if (doConv) {
        __syncthreads();
        floatx4 acc3[2][4];
#pragma unroll
        for (int i = 0; i < 2; ++i)
#pragma unroll
            for (int j = 0; j < 4; ++j) acc3[i][j] = zed;
#pragma unroll
        for (int ks = 0; ks < 4; ++ks) {
            int k = (ks << 5) + (quad << 3);
            short8 a[2], b[4];
#pragma unroll
            for (int i = 0; i < 2; ++i)
                a[i] = *(const short8*)(&ha_s[(wrb + (i << 4) + l16) * 136 + k]);
#pragma unroll
            for (int j = 0; j < 4; ++j)
                b[j] = *(const short8*)(Wc + (size_t)(wcb + (l16 << 2) + j) * HH + k);
#pragma unroll
            for (int i = 0; i < 2; ++i)
#pragma unroll
                for (int j = 0; j < 4; ++j)
                    acc3[i][j] =
                        __builtin_amdgcn_mfma_f32_16x16x32_bf16(a[i], b[j], acc3[i][j], 0, 0, 0);
        }
#pragma unroll
        for (int i = 0; i < 2; ++i) {
#pragma unroll
            for (int reg = 0; reg < 4; ++reg) {
                int r = rowBase + wrb + (i << 4) + (quad << 2) + reg;
                if (r < NN) {
                    float dv = dinv[r];
                    float o[4];
#pragma unroll
                    for (int j = 0; j < 4; ++j) o[j] = acc3[i][j][reg] * dv;
                    *(uint2*)(y_out + (size_t)r * HH + co) = pack4(o);
                }
            }
        }
    }
}

extern "C" void kernel_launch(void* const* d_in, const int* in_sizes, int n_in,
                              void* d_out, int out_size, void* d_ws, size_t ws_size,
                              hipStream_t stream) {
    const float* x = (const float*)d_in[0];
    const int* ei = (const int*)d_in[1];
    const int* batch = (const int*)d_in[2];
    const float* z_embed = (const float*)d_in[3];
    const float* extra_w = (const float*)d_in[4];
    const float* extra_b = (const float*)d_in[5];
    const float* conv_w = (const float*)d_in[6];
    const float* conv_b = (const float*)d_in[7];
    const float* gamma = (const float*)d_in[8];
    const float* beta = (const float*)d_in[9];
    const float* mean_scale = (const float*)d_in[10];
    const float* mlp_w1 = (const float*)d_in[11];
    const float* mlp_b1 = (const float*)d_in[12];
    const float* mlp_w2 = (const float*)d_in[13];
    const float* mlp_b2 = (const float*)d_in[14];
    float* h_out = (float*)d_out;

    char* wsB = (char*)d_ws;
    size_t off = 0;
    auto alloc = [&](size_t bytes) -> void* {
        void* p = (void*)(wsB + off);
        off = (off + bytes + 255) & ~(size_t)255;
        return p;
    };
    float* dinv = (float*)alloc((size_t)NN * 4);
    int* deg = (int*)alloc((size_t)NN * 4);
    int* cursor = (int*)alloc((size_t)NN * 4);
    int* rowptr = (int*)alloc((size_t)(NN + 1) * 4);
    int* bsum = (int*)alloc(128 * 4);
    int* boff = (int*)alloc(128 * 4);
    int* col = (int*)alloc((size_t)EE * 4);
    int* gptr = (int*)alloc((size_t)(GG + 1) * 4);
    float* c1t = (float*)alloc((size_t)GG * HH * 4);
    float* c0t = (float*)alloc((size_t)GG * HH * 4);
    float* S1g = (float*)alloc((size_t)GG * HH * 4);
    float* S2g = (float*)alloc((size_t)GG * HH * 4);
    unsigned short* wb =
        (unsigned short*)alloc((size_t)(LL * (HH * HH + MM * HH + HH * MM)) * 2);
    unsigned short* cwb = wb;
    unsigned short* w1b = wb + (size_t)LL * HH * HH;
    unsigned short* w2b = w1b + (size_t)LL * MM * HH;
    unsigned short* hb = (unsigned short*)alloc((size_t)NN * HH * 2);    // bf16 residual
    unsigned short* ybuf = (unsigned short*)alloc((size_t)NN * HH * 2);  // y (conv out)
    unsigned short* aggb = (unsigned short*)alloc((size_t)NN * HH * 2);  // agg bf16

    hipMemsetAsync(deg, 0, (size_t)NN * 4, stream);
    hipMemsetAsync(cursor, 0, (size_t)NN * 4, stream);
    hipMemsetAsync(S1g, 0, (size_t)GG * HH * 4, stream);
    hipMemsetAsync(S2g, 0, (size_t)GG * HH * 4, stream);

    k_embed<<<(NN * 32 + 255) / 256, 256, 0, stream>>>(x, z_embed, extra_w, extra_b, hb);
    {
        int n1 = LL * HH * HH, n2 = LL * MM * HH, n3 = LL * HH * MM;
        int nt = n1 + n2 + n3;
        k_f2bf3<<<(nt + 255) / 256, 256, 0, stream>>>(conv_w, cwb, n1, mlp_w1, w1b, n2,
                                                      mlp_w2, w2b, n3);
    }
    k_degree_p<<<1024, 256, 0, stream>>>(ei + EE, deg);
    k_dinv<<<(NN + 255) / 256, 256, 0, stream>>>(deg, dinv);
    k_scan1<<<SCAN_NB, 256, 0, stream>>>(deg, bsum);
    k_scan2<<<1, 128, 0, stream>>>(bsum, boff);
    k_scan3<<<SCAN_NB, 256, 0, stream>>>(deg, boff, rowptr);
    k_fill_p<<<1024, 256, 0, stream>>>(ei, rowptr, cursor, col);
    k_gptr<<<(NN + 255) / 256, 256, 0, stream>>>(batch, gptr);

    int gconv = (NN + 127) / 128;
    int gmega = (NN + 63) / 64;
    k_conv<<<gconv, 256, 0, stream>>>(hb, cwb, dinv, ybuf);
    for (int i = 0; i < LL; ++i) {
        k_agg<<<(NN + 3) / 4, 256, 0, stream>>>(ybuf, rowptr, col, dinv,
                                                conv_b + (size_t)i * HH, batch, aggb, S1g,
                                                S2g);
        k_finalize<<<GG, 128, 0, stream>>>(gptr, mean_scale + (size_t)i * HH,
                                           gamma + (size_t)i * HH, beta + (size_t)i * HH,
                                           S1g, S2g, c1t, c0t);
        k_mega<<<gmega, 256, 0, stream>>>(
            aggb, batch, c1t, c0t, w1b + (size_t)i * MM * HH, mlp_b1 + (size_t)i * MM,
            w2b + (size_t)i * HH * MM, mlp_b2 + (size_t)i * HH,
            cwb + (size_t)(i + 1 < LL ? i + 1 : 0) * HH * HH, dinv, hb, h_out, ybuf,
            i == LL - 1 ? 1 : 0, i < LL - 1 ? 1 : 0);
    }
}